// Round 1
// baseline (469.347 us; speedup 1.0000x reference)
//
#include <hip/hip_runtime.h>
#include <math.h>

#define BB 4
#define NXD 512
#define NYD 512
#define DVD 32
#define KXD 64
#define KYD 64

// workspace layout (float offsets)
#define OFF_DN  0            // DtabN [64][512]
#define OFF_DT  32768        // DtabT [512][64]
#define OFF_FCN 65536        // FtcN  [64][512]
#define OFF_FSN 98304        // FtsN  [64][512]
#define OFF_FCT 131072       // FtcT  [512][64]
#define OFF_FST 163840       // FtsT  [512][64]
#define OFF_C   196608       // C  [4][64ky][512nx][32dv]
#define OFF_FR  4390912      // Fr [4][64ky][64kx][32j]
#define OFF_FI  4915200
#define OFF_YR  5439488      // Yr [4][32i][64kx][64ky]
#define OFF_YI  5963776
#define OFF_G   6488064      // G  [4][512nx][32i][64ky]
// total = 10,682,368 floats = 42.7 MB

// async global->LDS, 16B per lane; LDS base must be wave-uniform (it is: wv-only)
__device__ __forceinline__ void gload_lds16(const float* g, float* l) {
    __builtin_amdgcn_global_load_lds(
        (const __attribute__((address_space(1))) void*)g,
        (__attribute__((address_space(3))) void*)l, 16, 0, 0);
}

__global__ __launch_bounds__(256) void k_tables(float* __restrict__ ws) {
    int idx = blockIdx.x * 256 + threadIdx.x;   // 0..32767
    int k = idx >> 9;                            // 0..63
    int n = idx & 511;                           // 0..511
    const float inv_sq512 = 0.04419417382415922f;  // 1/sqrt(512)
    float ak = (k == 0) ? inv_sq512 : 0.0625f;   // sqrt(2/512)=1/16
    int m = (k * (2 * n + 1)) & 2047;
    float d = ak * cospif((float)m * (1.0f / 1024.0f));
    ws[OFF_DN + k * 512 + n] = d;
    ws[OFF_DT + n * 64 + k] = d;
    int mf = (k * n) & 511;
    float c = cospif((float)mf * (1.0f / 256.0f)) * inv_sq512;
    float s = sinpif((float)mf * (1.0f / 256.0f)) * inv_sq512;
    ws[OFF_FCN + k * 512 + n] = c;
    ws[OFF_FSN + k * 512 + n] = s;
    ws[OFF_FCT + n * 64 + k] = c;
    ws[OFF_FST + n * 64 + k] = s;
}

// K1: DCT along NY, truncated.  block = (b, nx-pair); ny chunked 64.
// Double-buffered x staging via global_load_lds; D-table read direct from
// global (L1/L2-resident, identical across all blocks).  1 barrier/chunk.
__global__ __launch_bounds__(256) void k_dct(const float* __restrict__ x,
                                             const float* __restrict__ ws,
                                             float* __restrict__ C) {
    __shared__ __align__(16) float xs[2][2 * 2048];   // [buf][n*2048 + ny*32+dv] 32 KB
    int b = blockIdx.x >> 8;
    int nx = (blockIdx.x & 255) * 2;
    int t = threadIdx.x;
    int wv = t >> 6;
    int dv0 = (t & 15) * 2;
    int ky0 = (t >> 4) * 4;
    const float* Dt = ws + OFF_DT;   // [ny][64]
    const float* xb = x + (size_t)(b * NXD + nx) * NYD * DVD;

    auto stage = [&](int buf, int ch) {
#pragma unroll
        for (int n = 0; n < 2; ++n) {
            const float* src = xb + ((size_t)n * NYD + ch * 64) * DVD;
#pragma unroll
            for (int p = 0; p < 2; ++p) {
                int f = p * 256 + t;   // float4 index over 2048 floats
                gload_lds16(src + f * 4, xs[buf] + n * 2048 + (p * 256 + wv * 64) * 4);
            }
        }
    };

    float a[2][4][2] = {};
    stage(0, 0);
    __syncthreads();                 // drains vmcnt for chunk 0
    for (int ch = 0; ch < 8; ++ch) {
        int buf = ch & 1;
        if (ch < 7) stage(buf ^ 1, ch + 1);   // in flight during compute
        const float* dtc = Dt + ch * 4096 + ky0;
        const float* xsb = xs[buf];
#pragma unroll 4
        for (int nyc = 0; nyc < 64; ++nyc) {
            float4 d4 = *(const float4*)(dtc + nyc * 64);
            float2 x0 = *(const float2*)(xsb + nyc * 32 + dv0);
            float2 x1 = *(const float2*)(xsb + 2048 + nyc * 32 + dv0);
            float da[4] = {d4.x, d4.y, d4.z, d4.w};
#pragma unroll
            for (int q = 0; q < 4; ++q) {
                a[0][q][0] += da[q] * x0.x; a[0][q][1] += da[q] * x0.y;
                a[1][q][0] += da[q] * x1.x; a[1][q][1] += da[q] * x1.y;
            }
        }
        __syncthreads();             // drains next-chunk stage + protects buffer swap
    }
#pragma unroll
    for (int n = 0; n < 2; ++n)
#pragma unroll
        for (int q = 0; q < 4; ++q) {
            float2 v; v.x = a[n][q][0]; v.y = a[n][q][1];
            *(float2*)(C + ((size_t)((b * KYD + ky0 + q) * NXD + nx + n)) * DVD + dv0) = v;
        }
}

// K2: truncated rFFT along NX.  block = (b, ky, dv-half); nx chunked 256,
// double-buffered via global_load_lds; tables direct from global (L2).
__global__ __launch_bounds__(256) void k_rfft(const float* __restrict__ Cbuf,
                                              const float* __restrict__ ws,
                                              float* __restrict__ Fr,
                                              float* __restrict__ Fi) {
    __shared__ __align__(16) float cs[2][4096];   // 32 KB, [buf][nx(256)][16dv]
    int b = blockIdx.x >> 7;
    int r = blockIdx.x & 127;
    int ky = r >> 1;
    int dvbase = (r & 1) * 16;
    int t = threadIdx.x;
    int wv = t >> 6;
    int dv0 = (t & 7) * 2;
    int kx0 = (t >> 3) * 2;
    const float* Tc = ws + OFF_FCT;
    const float* Ts = ws + OFF_FST;
    const float* Cb = Cbuf + (size_t)(b * KYD + ky) * NXD * DVD + dvbase;

    auto stage = [&](int buf, int ch) {
#pragma unroll
        for (int p = 0; p < 4; ++p) {
            int fi4 = p * 256 + t;
            int row = fi4 >> 2, c4 = fi4 & 3;
            gload_lds16(Cb + (size_t)(ch * 256 + row) * DVD + c4 * 4,
                        cs[buf] + (p * 256 + wv * 64) * 4);
        }
    };

    float ar[2][2] = {}, ai[2][2] = {};
    stage(0, 0);
    __syncthreads();
    for (int ch = 0; ch < 2; ++ch) {
        if (ch == 0) stage(1, 1);    // overlaps with compute of chunk 0
        const float* csb = cs[ch];
        int nx0 = ch * 256;
#pragma unroll 8
        for (int nxc = 0; nxc < 256; ++nxc) {
            float2 cv = *(const float2*)(csb + nxc * 16 + dv0);
            float2 c2 = *(const float2*)(Tc + (nx0 + nxc) * 64 + kx0);
            float2 s2 = *(const float2*)(Ts + (nx0 + nxc) * 64 + kx0);
            ar[0][0] += c2.x * cv.x; ar[0][1] += c2.x * cv.y;
            ar[1][0] += c2.y * cv.x; ar[1][1] += c2.y * cv.y;
            ai[0][0] -= s2.x * cv.x; ai[0][1] -= s2.x * cv.y;
            ai[1][0] -= s2.y * cv.x; ai[1][1] -= s2.y * cv.y;
        }
        __syncthreads();
    }
#pragma unroll
    for (int q = 0; q < 2; ++q) {
        size_t o = ((size_t)((b * KYD + ky) * KXD + kx0 + q)) * DVD + dvbase + dv0;
        float2 vr; vr.x = ar[q][0]; vr.y = ar[q][1];
        float2 vi; vi.x = ai[q][0]; vi.y = ai[q][1];
        *(float2*)(Fr + o) = vr;
        *(float2*)(Fi + o) = vi;
    }
}

// K3: channel mix per (kx, i-quad, e-half).  grid = 64*8*2 (was *8): e split
// 2-way -> fl LDS 64->32 KB, 2->4 blocks/CU, 2x wave count for R latency.
__global__ __launch_bounds__(256) void k_mix(const float* __restrict__ Rr,
                                             const float* __restrict__ Ri,
                                             const float* __restrict__ Fr,
                                             const float* __restrict__ Fi,
                                             float* __restrict__ Yr,
                                             float* __restrict__ Yi) {
    __shared__ float fl[2 * 32 * 64 * 2];   // 32 KB, [e2][j][swz(ky)]{fr,fi}
    int kx = blockIdx.x & 63;
    int ig = (blockIdx.x >> 6) & 7;   // 0..7
    int eh = blockIdx.x >> 9;         // 0..1
    int t = threadIdx.x;
    int j = t & 31, kyb = t >> 5;     // kyb 0..7
#pragma unroll
    for (int e2 = 0; e2 < 2; ++e2) {
        int e = eh * 2 + e2;
#pragma unroll
        for (int p = 0; p < 8; ++p) {
            int ky = p * 8 + kyb;
            size_t go = ((size_t)((e * KYD + ky) * KXD + kx)) * DVD + j;
            int lo = ((e2 * 32 + j) * 64 + ((ky + j) & 63)) * 2;
            fl[lo] = Fr[go];
            fl[lo + 1] = Fi[go];
        }
    }
    __syncthreads();
    int lane = t & 63, w = t >> 6;
    int i = ig * 4 + w;
    size_t rb = (size_t)(i * 32) * 4096 + kx * 64 + lane;
    float yr[2] = {}, yi[2] = {};
#pragma unroll 8
    for (int jj = 0; jj < 32; ++jj) {
        float rr = Rr[rb + (size_t)jj * 4096];
        float ri = Ri[rb + (size_t)jj * 4096];
#pragma unroll
        for (int e2 = 0; e2 < 2; ++e2) {
            float2 f = *(const float2*)(fl + ((e2 * 32 + jj) * 64 + ((lane + jj) & 63)) * 2);
            yr[e2] += rr * f.x - ri * f.y;
            yi[e2] += rr * f.y + ri * f.x;
        }
    }
#pragma unroll
    for (int e2 = 0; e2 < 2; ++e2) {
        int e = eh * 2 + e2;
        size_t o = ((size_t)((e * DVD + i) * KXD + kx)) * KYD + lane;
        Yr[o] = yr[e2];
        Yi[o] = yi[e2];
    }
}

// K4: truncated irFFT along NX.  block = (b, i, nx-octant); grid 1024.
// Y staging vectorized to float4.
__global__ __launch_bounds__(256) void k_irfft(const float* __restrict__ Yr,
                                               const float* __restrict__ Yi,
                                               const float* __restrict__ ws,
                                               float* __restrict__ G) {
    __shared__ __align__(16) float ylr[64 * 64];   // 16 KB [kx][ky], pre-weighted
    __shared__ __align__(16) float yli[64 * 64];
    int blk = blockIdx.x;
    int oct = blk & 7;
    int i = (blk >> 3) & 31;
    int b = blk >> 8;
    int t = threadIdx.x;
    size_t ybase = ((size_t)(b * DVD + i)) * KXD * KYD;
#pragma unroll
    for (int p = 0; p < 4; ++p) {
        int f = p * 256 + t;            // float4 index over 1024; f<16 <=> kx==0
        float wk = (f < 16) ? 1.0f : 2.0f;
        float4 vr = *(const float4*)(Yr + ybase + (size_t)f * 4);
        float4 vi = *(const float4*)(Yi + ybase + (size_t)f * 4);
        vr.x *= wk; vr.y *= wk; vr.z *= wk; vr.w *= wk;
        vi.x *= wk; vi.y *= wk; vi.z *= wk; vi.w *= wk;
        *(float4*)(ylr + f * 4) = vr;
        *(float4*)(yli + f * 4) = vi;
    }
    __syncthreads();
    int kyg = t & 15, nxg = t >> 4;
    int ky0 = kyg * 4;
    int gnx0 = oct * 64 + nxg * 4;
    const float* Tc = ws + OFF_FCN;   // [kx][nx]
    const float* Ts = ws + OFF_FSN;
    float acc[4][4] = {};
    for (int kx = 0; kx < 64; ++kx) {
        float4 cv = *(const float4*)(Tc + kx * 512 + gnx0);
        float4 sv = *(const float4*)(Ts + kx * 512 + gnx0);
        float4 vr = *(const float4*)(ylr + kx * 64 + ky0);
        float4 vi = *(const float4*)(yli + kx * 64 + ky0);
        float ca[4] = {cv.x, cv.y, cv.z, cv.w};
        float sa[4] = {sv.x, sv.y, sv.z, sv.w};
        float ra[4] = {vr.x, vr.y, vr.z, vr.w};
        float ia[4] = {vi.x, vi.y, vi.z, vi.w};
#pragma unroll
        for (int q = 0; q < 4; ++q)
#pragma unroll
            for (int kk = 0; kk < 4; ++kk)
                acc[q][kk] += ca[q] * ra[kk] - sa[q] * ia[kk];
    }
#pragma unroll
    for (int q = 0; q < 4; ++q) {
        float4 v; v.x = acc[q][0]; v.y = acc[q][1]; v.z = acc[q][2]; v.w = acc[q][3];
        *(float4*)(G + (((size_t)(b * NXD + gnx0 + q)) * DVD + i) * KYD + ky0) = v;
    }
}

// K5: iDCT along NY.  block = (b, nx-pair).  Dn table read direct from global
// (shared across all blocks, L1/L2) -> zero barriers in the main loop.
#define GST 68
__global__ __launch_bounds__(256) void k_idct(const float* __restrict__ G,
                                              const float* __restrict__ ws,
                                              float* __restrict__ out) {
    __shared__ __align__(16) float gs[2][32 * GST];   // 17.4 KB
    int b = blockIdx.x >> 8;
    int nx = (blockIdx.x & 255) * 2;
    int t = threadIdx.x;
    int ig = t & 15, nyg = t >> 4;
    int i0 = ig * 2;
    const float* Dn = ws + OFF_DN;   // [ky][512ny]
#pragma unroll
    for (int n = 0; n < 2; ++n) {
        const float4* src = (const float4*)(G + (size_t)(b * NXD + nx + n) * DVD * KYD);
#pragma unroll
        for (int p = 0; p < 2; ++p) {
            int f = p * 256 + t;           // 512 float4 = [32i][64ky]
            int i = f >> 4, ky4 = (f & 15) * 4;
            *(float4*)(gs[n] + i * GST + ky4) = src[f];
        }
    }
    __syncthreads();
    float* outb = out + ((size_t)(b * NXD + nx)) * NYD * DVD;
    for (int c = 0; c < 8; ++c) {
        const float* dnc = Dn + c * 64 + nyg * 4;
        float acc[2][4][2] = {};
#pragma unroll 2
        for (int kyc = 0; kyc < 16; ++kyc) {
            int ky0 = kyc * 4;
            float4 g00 = *(const float4*)(gs[0] + i0 * GST + ky0);
            float4 g01 = *(const float4*)(gs[0] + (i0 + 1) * GST + ky0);
            float4 g10 = *(const float4*)(gs[1] + i0 * GST + ky0);
            float4 g11 = *(const float4*)(gs[1] + (i0 + 1) * GST + ky0);
            float g0a[2][4] = {{g00.x, g00.y, g00.z, g00.w}, {g10.x, g10.y, g10.z, g10.w}};
            float g1a[2][4] = {{g01.x, g01.y, g01.z, g01.w}, {g11.x, g11.y, g11.z, g11.w}};
#pragma unroll
            for (int kk = 0; kk < 4; ++kk) {
                float4 dv = *(const float4*)(dnc + (ky0 + kk) * 512);
                float da[4] = {dv.x, dv.y, dv.z, dv.w};
#pragma unroll
                for (int q = 0; q < 4; ++q) {
                    acc[0][q][0] += da[q] * g0a[0][kk];
                    acc[0][q][1] += da[q] * g1a[0][kk];
                    acc[1][q][0] += da[q] * g0a[1][kk];
                    acc[1][q][1] += da[q] * g1a[1][kk];
                }
            }
        }
        int ny0 = c * 64 + nyg * 4;
#pragma unroll
        for (int n = 0; n < 2; ++n)
#pragma unroll
            for (int q = 0; q < 4; ++q) {
                float2 v; v.x = acc[n][q][0]; v.y = acc[n][q][1];
                *(float2*)(outb + ((size_t)n * NYD + ny0 + q) * DVD + i0) = v;
            }
    }
}

extern "C" void kernel_launch(void* const* d_in, const int* in_sizes, int n_in,
                              void* d_out, int out_size, void* d_ws, size_t ws_size,
                              hipStream_t stream) {
    const float* x  = (const float*)d_in[0];
    const float* Rr = (const float*)d_in[1];
    const float* Ri = (const float*)d_in[2];
    float* out = (float*)d_out;
    float* ws  = (float*)d_ws;
    float* C   = ws + OFF_C;
    float* Fr  = ws + OFF_FR;
    float* Fi  = ws + OFF_FI;
    float* Yr  = ws + OFF_YR;
    float* Yi  = ws + OFF_YI;
    float* G   = ws + OFF_G;

    k_tables<<<128, 256, 0, stream>>>(ws);
    k_dct<<<BB * (NXD / 2), 256, 0, stream>>>(x, ws, C);
    k_rfft<<<BB * KYD * 2, 256, 0, stream>>>(C, ws, Fr, Fi);
    k_mix<<<KXD * 8 * 2, 256, 0, stream>>>(Rr, Ri, Fr, Fi, Yr, Yi);
    k_irfft<<<BB * DVD * 8, 256, 0, stream>>>(Yr, Yi, ws, G);
    k_idct<<<BB * NXD / 2, 256, 0, stream>>>(G, ws, out);
}

// Round 2
// 405.723 us; speedup vs baseline: 1.1568x; 1.1568x over previous
//
#include <hip/hip_runtime.h>
#include <math.h>

#define BB 4
#define NXD 512
#define NYD 512
#define DVD 32
#define KXD 64
#define KYD 64

// workspace layout (float offsets)
#define OFF_DN  0            // DtabN [64][512]
#define OFF_DT  32768        // DtabT [512][64]
#define OFF_FCN 65536        // FtcN  [64][512]
#define OFF_FSN 98304        // FtsN  [64][512]
#define OFF_FI2 131072       // Ft interleaved [512nx][64kx]{c,s}  (reuses old FCT+FST space)
#define OFF_C   196608       // C  [4][64ky][512nx][32dv]
#define OFF_FR  4390912      // Fr [4][64ky][64kx][32j]
#define OFF_FI  4915200
#define OFF_YR  5439488      // Yr [4][32i][64kx][64ky]
#define OFF_YI  5963776
#define OFF_G   6488064      // G  [4][512nx][32i][64ky]
// total = 10,682,368 floats = 42.7 MB

// async global->LDS, 16B per lane; LDS dest is wave-uniform base + lane*16.
// RULE (R1 post-mortem): while these are in flight, the compute loop must not
// contain ANY global loads - vmcnt is in-order, so a wait for an in-loop load
// drains the prefetch queue and serializes the pipeline.
__device__ __forceinline__ void gload_lds16(const float* g, float* l) {
    __builtin_amdgcn_global_load_lds(
        (const __attribute__((address_space(1))) void*)g,
        (__attribute__((address_space(3))) void*)l, 16, 0, 0);
}

__global__ __launch_bounds__(256) void k_tables(float* __restrict__ ws) {
    int idx = blockIdx.x * 256 + threadIdx.x;   // 0..32767
    int k = idx >> 9;                            // 0..63
    int n = idx & 511;                           // 0..511
    const float inv_sq512 = 0.04419417382415922f;  // 1/sqrt(512)
    float ak = (k == 0) ? inv_sq512 : 0.0625f;   // sqrt(2/512)=1/16
    int m = (k * (2 * n + 1)) & 2047;
    float d = ak * cospif((float)m * (1.0f / 1024.0f));
    ws[OFF_DN + k * 512 + n] = d;
    ws[OFF_DT + n * 64 + k] = d;
    int mf = (k * n) & 511;
    float c = cospif((float)mf * (1.0f / 256.0f)) * inv_sq512;
    float s = sinpif((float)mf * (1.0f / 256.0f)) * inv_sq512;
    ws[OFF_FCN + k * 512 + n] = c;
    ws[OFF_FSN + k * 512 + n] = s;
    ws[OFF_FI2 + (n * 64 + k) * 2 + 0] = c;   // interleaved for k_rfft b128 loads
    ws[OFF_FI2 + (n * 64 + k) * 2 + 1] = s;
}

// K1: DCT along NY, truncated.  block = (b, nx-pair); ny chunked 32.
// x AND D-table chunks both double-buffered via global_load_lds; inner loop is
// pure LDS+FMA (no global loads -> no vmcnt ordering hazard).  1 barrier/chunk.
__global__ __launch_bounds__(256) void k_dct(const float* __restrict__ x,
                                             const float* __restrict__ ws,
                                             float* __restrict__ C) {
    __shared__ __align__(16) float xs[2][2][1024];   // [buf][n][32ny*32dv] 16 KB
    __shared__ __align__(16) float dt[2][2048];      // [buf][32ny*64ky]    16 KB
    int b = blockIdx.x >> 8;
    int nx = (blockIdx.x & 255) * 2;
    int t = threadIdx.x;
    int wv = t >> 6;
    int dv0 = (t & 15) * 2;
    int ky0 = (t >> 4) * 4;
    const float* Dt = ws + OFF_DT;   // [ny][64]
    const float* xb = x + (size_t)(b * NXD + nx) * NYD * DVD;

    auto stage = [&](int buf, int ch) {
#pragma unroll
        for (int n = 0; n < 2; ++n)
            gload_lds16(xb + (size_t)(n * 512 + ch * 32) * 32 + t * 4,
                        &xs[buf][n][wv * 256]);
#pragma unroll
        for (int p = 0; p < 2; ++p)
            gload_lds16(Dt + ch * 2048 + (p * 256 + t) * 4,
                        &dt[buf][(p * 256 + wv * 64) * 4]);
    };

    float a[2][4][2] = {};
    stage(0, 0);
    __syncthreads();                 // drains vmcnt for chunk 0
    for (int ch = 0; ch < 16; ++ch) {
        int buf = ch & 1;
        if (ch < 15) stage(buf ^ 1, ch + 1);   // in flight across the compute
        const float* dtc = &dt[buf][ky0];
        const float* x0p = &xs[buf][0][dv0];
        const float* x1p = &xs[buf][1][dv0];
#pragma unroll 4
        for (int nyc = 0; nyc < 32; ++nyc) {
            float4 d4 = *(const float4*)(dtc + nyc * 64);
            float2 x0 = *(const float2*)(x0p + nyc * 32);
            float2 x1 = *(const float2*)(x1p + nyc * 32);
            float da[4] = {d4.x, d4.y, d4.z, d4.w};
#pragma unroll
            for (int q = 0; q < 4; ++q) {
                a[0][q][0] += da[q] * x0.x; a[0][q][1] += da[q] * x0.y;
                a[1][q][0] += da[q] * x1.x; a[1][q][1] += da[q] * x1.y;
            }
        }
        __syncthreads();             // drains next-chunk prefetch + buffer swap
    }
#pragma unroll
    for (int n = 0; n < 2; ++n)
#pragma unroll
        for (int q = 0; q < 4; ++q) {
            float2 v; v.x = a[n][q][0]; v.y = a[n][q][1];
            *(float2*)(C + ((size_t)((b * KYD + ky0 + q) * NXD + nx + n)) * DVD + dv0) = v;
        }
}

// K2: truncated rFFT along NX.  block = (b, ky, dv-half); nx chunked 256.
// Regular-load staging (table slice per chunk is 128 KB -> must stay in-loop
// global, so no gload_lds prefetch allowed here).  Interleaved {c,s} table:
// one b128 per iteration instead of two b64.
__global__ __launch_bounds__(256) void k_rfft(const float* __restrict__ Cbuf,
                                              const float* __restrict__ ws,
                                              float* __restrict__ Fr,
                                              float* __restrict__ Fi) {
    __shared__ __align__(16) float cs[256 * 16];   // 16 KB
    int b = blockIdx.x >> 7;
    int r = blockIdx.x & 127;
    int ky = r >> 1;
    int dvbase = (r & 1) * 16;
    int t = threadIdx.x;
    int dv0 = (t & 7) * 2;
    int kx0 = (t >> 3) * 2;
    const float* T2 = ws + OFF_FI2;   // [nx][kx]{c,s}
    float ar[2][2] = {}, ai[2][2] = {};
    for (int ch = 0; ch < 2; ++ch) {
        int nx0 = ch * 256;
        __syncthreads();
#pragma unroll
        for (int p = 0; p < 4; ++p) {
            int fi4 = p * 256 + t;
            int row = fi4 >> 2, c4 = fi4 & 3;
            *(float4*)(cs + row * 16 + c4 * 4) =
                *(const float4*)(Cbuf + ((size_t)(b * KYD + ky) * NXD + nx0 + row) * DVD + dvbase + c4 * 4);
        }
        __syncthreads();
#pragma unroll 8
        for (int nxc = 0; nxc < 256; ++nxc) {
            float2 cv = *(const float2*)(cs + nxc * 16 + dv0);
            float4 q = *(const float4*)(T2 + ((nx0 + nxc) * 64 + kx0) * 2);  // c0,s0,c1,s1
            ar[0][0] += q.x * cv.x; ar[0][1] += q.x * cv.y;
            ai[0][0] -= q.y * cv.x; ai[0][1] -= q.y * cv.y;
            ar[1][0] += q.z * cv.x; ar[1][1] += q.z * cv.y;
            ai[1][0] -= q.w * cv.x; ai[1][1] -= q.w * cv.y;
        }
    }
#pragma unroll
    for (int q = 0; q < 2; ++q) {
        size_t o = ((size_t)((b * KYD + ky) * KXD + kx0 + q)) * DVD + dvbase + dv0;
        float2 vr; vr.x = ar[q][0]; vr.y = ar[q][1];
        float2 vi; vi.x = ai[q][0]; vi.y = ai[q][1];
        *(float2*)(Fr + o) = vr;
        *(float2*)(Fi + o) = vi;
    }
}

// K3: channel mix per (kx, i-quad, e-half).  grid = 64*8*2: e split 2-way ->
// fl LDS 32 KB, 4 blocks/CU for R-load latency hiding.
__global__ __launch_bounds__(256) void k_mix(const float* __restrict__ Rr,
                                             const float* __restrict__ Ri,
                                             const float* __restrict__ Fr,
                                             const float* __restrict__ Fi,
                                             float* __restrict__ Yr,
                                             float* __restrict__ Yi) {
    __shared__ float fl[2 * 32 * 64 * 2];   // 32 KB, [e2][j][swz(ky)]{fr,fi}
    int kx = blockIdx.x & 63;
    int ig = (blockIdx.x >> 6) & 7;   // 0..7
    int eh = blockIdx.x >> 9;         // 0..1
    int t = threadIdx.x;
    int j = t & 31, kyb = t >> 5;     // kyb 0..7
#pragma unroll
    for (int e2 = 0; e2 < 2; ++e2) {
        int e = eh * 2 + e2;
#pragma unroll
        for (int p = 0; p < 8; ++p) {
            int ky = p * 8 + kyb;
            size_t go = ((size_t)((e * KYD + ky) * KXD + kx)) * DVD + j;
            int lo = ((e2 * 32 + j) * 64 + ((ky + j) & 63)) * 2;
            fl[lo] = Fr[go];
            fl[lo + 1] = Fi[go];
        }
    }
    __syncthreads();
    int lane = t & 63, w = t >> 6;
    int i = ig * 4 + w;
    size_t rb = (size_t)(i * 32) * 4096 + kx * 64 + lane;
    float yr[2] = {}, yi[2] = {};
#pragma unroll 8
    for (int jj = 0; jj < 32; ++jj) {
        float rr = Rr[rb + (size_t)jj * 4096];
        float ri = Ri[rb + (size_t)jj * 4096];
#pragma unroll
        for (int e2 = 0; e2 < 2; ++e2) {
            float2 f = *(const float2*)(fl + ((e2 * 32 + jj) * 64 + ((lane + jj) & 63)) * 2);
            yr[e2] += rr * f.x - ri * f.y;
            yi[e2] += rr * f.y + ri * f.x;
        }
    }
#pragma unroll
    for (int e2 = 0; e2 < 2; ++e2) {
        int e = eh * 2 + e2;
        size_t o = ((size_t)((e * DVD + i) * KXD + kx)) * KYD + lane;
        Yr[o] = yr[e2];
        Yi[o] = yi[e2];
    }
}

// K4: truncated irFFT along NX.  block = (b, i, nx-octant); grid 1024.
__global__ __launch_bounds__(256) void k_irfft(const float* __restrict__ Yr,
                                               const float* __restrict__ Yi,
                                               const float* __restrict__ ws,
                                               float* __restrict__ G) {
    __shared__ __align__(16) float ylr[64 * 64];   // 16 KB [kx][ky], pre-weighted
    __shared__ __align__(16) float yli[64 * 64];
    int blk = blockIdx.x;
    int oct = blk & 7;
    int i = (blk >> 3) & 31;
    int b = blk >> 8;
    int t = threadIdx.x;
    size_t ybase = ((size_t)(b * DVD + i)) * KXD * KYD;
#pragma unroll
    for (int p = 0; p < 4; ++p) {
        int f = p * 256 + t;            // float4 index over 1024; f<16 <=> kx==0
        float wk = (f < 16) ? 1.0f : 2.0f;
        float4 vr = *(const float4*)(Yr + ybase + (size_t)f * 4);
        float4 vi = *(const float4*)(Yi + ybase + (size_t)f * 4);
        vr.x *= wk; vr.y *= wk; vr.z *= wk; vr.w *= wk;
        vi.x *= wk; vi.y *= wk; vi.z *= wk; vi.w *= wk;
        *(float4*)(ylr + f * 4) = vr;
        *(float4*)(yli + f * 4) = vi;
    }
    __syncthreads();
    int kyg = t & 15, nxg = t >> 4;
    int ky0 = kyg * 4;
    int gnx0 = oct * 64 + nxg * 4;
    const float* Tc = ws + OFF_FCN;   // [kx][nx]
    const float* Ts = ws + OFF_FSN;
    float acc[4][4] = {};
    for (int kx = 0; kx < 64; ++kx) {
        float4 cv = *(const float4*)(Tc + kx * 512 + gnx0);
        float4 sv = *(const float4*)(Ts + kx * 512 + gnx0);
        float4 vr = *(const float4*)(ylr + kx * 64 + ky0);
        float4 vi = *(const float4*)(yli + kx * 64 + ky0);
        float ca[4] = {cv.x, cv.y, cv.z, cv.w};
        float sa[4] = {sv.x, sv.y, sv.z, sv.w};
        float ra[4] = {vr.x, vr.y, vr.z, vr.w};
        float ia[4] = {vi.x, vi.y, vi.z, vi.w};
#pragma unroll
        for (int q = 0; q < 4; ++q)
#pragma unroll
            for (int kk = 0; kk < 4; ++kk)
                acc[q][kk] += ca[q] * ra[kk] - sa[q] * ia[kk];
    }
#pragma unroll
    for (int q = 0; q < 4; ++q) {
        float4 v; v.x = acc[q][0]; v.y = acc[q][1]; v.z = acc[q][2]; v.w = acc[q][3];
        *(float4*)(G + (((size_t)(b * NXD + gnx0 + q)) * DVD + i) * KYD + ky0) = v;
    }
}

// K5: iDCT along NY.  block = (b, nx-pair).  Dn chunk double-buffered via
// global_load_lds (inner loop pure LDS+FMA; out stores don't need vmcnt waits).
#define GST 68
__global__ __launch_bounds__(256) void k_idct(const float* __restrict__ G,
                                              const float* __restrict__ ws,
                                              float* __restrict__ out) {
    __shared__ __align__(16) float gs[2][32 * GST];   // 17.4 KB ([n] index, not dbuf)
    __shared__ __align__(16) float dn[2][4096];       // 32 KB dbuf [64ky][64ny]
    int b = blockIdx.x >> 8;
    int nx = (blockIdx.x & 255) * 2;
    int t = threadIdx.x;
    int wv = t >> 6;
    int ig = t & 15, nyg = t >> 4;
    int i0 = ig * 2;
    const float* Dn = ws + OFF_DN;   // [ky][512ny]

    auto stage_dn = [&](int buf, int ch) {
#pragma unroll
        for (int p = 0; p < 4; ++p) {
            int f = p * 256 + t;       // 1024 float4
            int ky = f >> 4, ny4 = (f & 15) * 4;
            gload_lds16(Dn + ky * 512 + ch * 64 + ny4,
                        &dn[buf][(p * 256 + wv * 64) * 4]);
        }
    };

#pragma unroll
    for (int n = 0; n < 2; ++n) {
        const float4* src = (const float4*)(G + (size_t)(b * NXD + nx + n) * DVD * KYD);
#pragma unroll
        for (int p = 0; p < 2; ++p) {
            int f = p * 256 + t;           // 512 float4 = [32i][64ky]
            int i = f >> 4, ky4 = (f & 15) * 4;
            *(float4*)(gs[n] + i * GST + ky4) = src[f];
        }
    }
    stage_dn(0, 0);
    __syncthreads();
    float* outb = out + ((size_t)(b * NXD + nx)) * NYD * DVD;
    for (int c = 0; c < 8; ++c) {
        int buf = c & 1;
        if (c < 7) stage_dn(buf ^ 1, c + 1);
        float acc[2][4][2] = {};
#pragma unroll 2
        for (int kyc = 0; kyc < 16; ++kyc) {
            int ky0 = kyc * 4;
            float4 g00 = *(const float4*)(gs[0] + i0 * GST + ky0);
            float4 g01 = *(const float4*)(gs[0] + (i0 + 1) * GST + ky0);
            float4 g10 = *(const float4*)(gs[1] + i0 * GST + ky0);
            float4 g11 = *(const float4*)(gs[1] + (i0 + 1) * GST + ky0);
            float g0a[2][4] = {{g00.x, g00.y, g00.z, g00.w}, {g10.x, g10.y, g10.z, g10.w}};
            float g1a[2][4] = {{g01.x, g01.y, g01.z, g01.w}, {g11.x, g11.y, g11.z, g11.w}};
#pragma unroll
            for (int kk = 0; kk < 4; ++kk) {
                float4 dv = *(const float4*)(&dn[buf][(ky0 + kk) * 64 + nyg * 4]);
                float da[4] = {dv.x, dv.y, dv.z, dv.w};
#pragma unroll
                for (int q = 0; q < 4; ++q) {
                    acc[0][q][0] += da[q] * g0a[0][kk];
                    acc[0][q][1] += da[q] * g1a[0][kk];
                    acc[1][q][0] += da[q] * g0a[1][kk];
                    acc[1][q][1] += da[q] * g1a[1][kk];
                }
            }
        }
        int ny0 = c * 64 + nyg * 4;
#pragma unroll
        for (int n = 0; n < 2; ++n)
#pragma unroll
            for (int q = 0; q < 4; ++q) {
                float2 v; v.x = acc[n][q][0]; v.y = acc[n][q][1];
                *(float2*)(outb + ((size_t)n * NYD + ny0 + q) * DVD + i0) = v;
            }
        __syncthreads();
    }
}

extern "C" void kernel_launch(void* const* d_in, const int* in_sizes, int n_in,
                              void* d_out, int out_size, void* d_ws, size_t ws_size,
                              hipStream_t stream) {
    const float* x  = (const float*)d_in[0];
    const float* Rr = (const float*)d_in[1];
    const float* Ri = (const float*)d_in[2];
    float* out = (float*)d_out;
    float* ws  = (float*)d_ws;
    float* C   = ws + OFF_C;
    float* Fr  = ws + OFF_FR;
    float* Fi  = ws + OFF_FI;
    float* Yr  = ws + OFF_YR;
    float* Yi  = ws + OFF_YI;
    float* G   = ws + OFF_G;

    k_tables<<<128, 256, 0, stream>>>(ws);
    k_dct<<<BB * (NXD / 2), 256, 0, stream>>>(x, ws, C);
    k_rfft<<<BB * KYD * 2, 256, 0, stream>>>(C, ws, Fr, Fi);
    k_mix<<<KXD * 8 * 2, 256, 0, stream>>>(Rr, Ri, Fr, Fi, Yr, Yi);
    k_irfft<<<BB * DVD * 8, 256, 0, stream>>>(Yr, Yi, ws, G);
    k_idct<<<BB * NXD / 2, 256, 0, stream>>>(G, ws, out);
}

// Round 3
// 404.387 us; speedup vs baseline: 1.1606x; 1.0033x over previous
//
#include <hip/hip_runtime.h>
#include <math.h>

#define BB 4
#define NXD 512
#define NYD 512
#define DVD 32
#define KXD 64
#define KYD 64

// workspace layout (float offsets)
#define OFF_DN  0            // DtabN [64][512]
#define OFF_DT  32768        // DtabT [512][64]
#define OFF_FCN 65536        // FtcN  [64][512]
#define OFF_FSN 98304        // FtsN  [64][512]
#define OFF_FI2 131072       // Ft interleaved [512nx][64kx]{c,s}
#define OFF_C   196608       // C  [4][64ky][512nx][32dv]
#define OFF_FR  4390912      // Fr [4][64ky][64kx][32j]
#define OFF_FI  4915200
#define OFF_YR  5439488      // Yr [4][32i][64kx][64ky]
#define OFF_YI  5963776
#define OFF_G   6488064      // G  [4][512nx][32i][64ky]
// total = 10,682,368 floats = 42.7 MB

// async global->LDS, 16B per lane; LDS dest is wave-uniform base + lane*16.
// RULE (R1 post-mortem): while these are in flight, the compute loop must not
// contain ANY global loads - vmcnt is in-order, so a wait for an in-loop load
// drains the prefetch queue and serializes the pipeline.
__device__ __forceinline__ void gload_lds16(const float* g, float* l) {
    __builtin_amdgcn_global_load_lds(
        (const __attribute__((address_space(1))) void*)g,
        (__attribute__((address_space(3))) void*)l, 16, 0, 0);
}

__global__ __launch_bounds__(256) void k_tables(float* __restrict__ ws) {
    int idx = blockIdx.x * 256 + threadIdx.x;   // 0..32767
    int k = idx >> 9;                            // 0..63
    int n = idx & 511;                           // 0..511
    const float inv_sq512 = 0.04419417382415922f;  // 1/sqrt(512)
    float ak = (k == 0) ? inv_sq512 : 0.0625f;   // sqrt(2/512)=1/16
    int m = (k * (2 * n + 1)) & 2047;
    float d = ak * cospif((float)m * (1.0f / 1024.0f));
    ws[OFF_DN + k * 512 + n] = d;
    ws[OFF_DT + n * 64 + k] = d;
    int mf = (k * n) & 511;
    float c = cospif((float)mf * (1.0f / 256.0f)) * inv_sq512;
    float s = sinpif((float)mf * (1.0f / 256.0f)) * inv_sq512;
    ws[OFF_FCN + k * 512 + n] = c;
    ws[OFF_FSN + k * 512 + n] = s;
    ws[OFF_FI2 + (n * 64 + k) * 2 + 0] = c;
    ws[OFF_FI2 + (n * 64 + k) * 2 + 1] = s;
}

// K1: DCT along NY.  block = (b, nx-pair), 128 threads; ny chunked 32, dbuf.
// Per-thread tile 2nx x 4ky x 4dv = 32 acc: per nyc, 3x ds_read_b128 feed
// 32 FMA (was 3 reads : 16 FMA).  All LDS read starts verified 8-distinct-bank.
__global__ __launch_bounds__(128) void k_dct(const float* __restrict__ x,
                                             const float* __restrict__ ws,
                                             float* __restrict__ C) {
    __shared__ __align__(16) float xs[2][2][1024];   // [buf][n][32ny*32dv] 16 KB
    __shared__ __align__(16) float dt[2][2048];      // [buf][32ny][64ky]   16 KB
    int b = blockIdx.x >> 8;
    int nx = (blockIdx.x & 255) * 2;
    int t = threadIdx.x;            // 0..127
    int wv = t >> 6;                // 0..1
    int dv0 = (t & 7) * 4;          // 8 groups x 4 dv
    int ky0 = (t >> 3) * 4;         // 16 groups x 4 ky
    const float* Dt = ws + OFF_DT;  // [ny][64ky]
    const float* xb = x + (size_t)(b * NXD + nx) * NYD * DVD;

    auto stage = [&](int buf, int ch) {
#pragma unroll
        for (int n = 0; n < 2; ++n)
#pragma unroll
            for (int p = 0; p < 2; ++p)
                gload_lds16(xb + (size_t)(n * 512 + ch * 32) * 32 + (p * 128 + t) * 4,
                            &xs[buf][n][(p * 128 + wv * 64) * 4]);
#pragma unroll
        for (int p = 0; p < 4; ++p)
            gload_lds16(Dt + ch * 2048 + (p * 128 + t) * 4,
                        &dt[buf][(p * 128 + wv * 64) * 4]);
    };

    float acc[2][4][4] = {};        // [n][q=ky][d=dv]
    stage(0, 0);
    __syncthreads();                // drains vmcnt for chunk 0
    for (int ch = 0; ch < 16; ++ch) {
        int buf = ch & 1;
        if (ch < 15) stage(buf ^ 1, ch + 1);   // in flight across compute
        const float* dtc = &dt[buf][ky0];
        const float* x0p = &xs[buf][0][dv0];
        const float* x1p = &xs[buf][1][dv0];
#pragma unroll 4
        for (int nyc = 0; nyc < 32; ++nyc) {
            float4 d4 = *(const float4*)(dtc + nyc * 64);
            float4 x0 = *(const float4*)(x0p + nyc * 32);
            float4 x1 = *(const float4*)(x1p + nyc * 32);
            float da[4] = {d4.x, d4.y, d4.z, d4.w};
            float xa[2][4] = {{x0.x, x0.y, x0.z, x0.w}, {x1.x, x1.y, x1.z, x1.w}};
#pragma unroll
            for (int q = 0; q < 4; ++q)
#pragma unroll
                for (int d = 0; d < 4; ++d) {
                    acc[0][q][d] += da[q] * xa[0][d];
                    acc[1][q][d] += da[q] * xa[1][d];
                }
        }
        __syncthreads();
    }
#pragma unroll
    for (int n = 0; n < 2; ++n)
#pragma unroll
        for (int q = 0; q < 4; ++q) {
            float4 v; v.x = acc[n][q][0]; v.y = acc[n][q][1];
            v.z = acc[n][q][2]; v.w = acc[n][q][3];
            *(float4*)(C + ((size_t)((b * KYD + ky0 + q) * NXD + nx + n)) * DVD + dv0) = v;
        }
}

// K2: truncated rFFT along NX.  block = (b, ky, dv-half); nx chunked 256.
// Interleaved {c,s} table read in-loop from global (L2-resident).
__global__ __launch_bounds__(256) void k_rfft(const float* __restrict__ Cbuf,
                                              const float* __restrict__ ws,
                                              float* __restrict__ Fr,
                                              float* __restrict__ Fi) {
    __shared__ __align__(16) float cs[256 * 16];   // 16 KB
    int b = blockIdx.x >> 7;
    int r = blockIdx.x & 127;
    int ky = r >> 1;
    int dvbase = (r & 1) * 16;
    int t = threadIdx.x;
    int dv0 = (t & 7) * 2;
    int kx0 = (t >> 3) * 2;
    const float* T2 = ws + OFF_FI2;   // [nx][kx]{c,s}
    float ar[2][2] = {}, ai[2][2] = {};
    for (int ch = 0; ch < 2; ++ch) {
        int nx0 = ch * 256;
        __syncthreads();
#pragma unroll
        for (int p = 0; p < 4; ++p) {
            int fi4 = p * 256 + t;
            int row = fi4 >> 2, c4 = fi4 & 3;
            *(float4*)(cs + row * 16 + c4 * 4) =
                *(const float4*)(Cbuf + ((size_t)(b * KYD + ky) * NXD + nx0 + row) * DVD + dvbase + c4 * 4);
        }
        __syncthreads();
#pragma unroll 8
        for (int nxc = 0; nxc < 256; ++nxc) {
            float2 cv = *(const float2*)(cs + nxc * 16 + dv0);
            float4 q = *(const float4*)(T2 + ((nx0 + nxc) * 64 + kx0) * 2);  // c0,s0,c1,s1
            ar[0][0] += q.x * cv.x; ar[0][1] += q.x * cv.y;
            ai[0][0] -= q.y * cv.x; ai[0][1] -= q.y * cv.y;
            ar[1][0] += q.z * cv.x; ar[1][1] += q.z * cv.y;
            ai[1][0] -= q.w * cv.x; ai[1][1] -= q.w * cv.y;
        }
    }
#pragma unroll
    for (int q = 0; q < 2; ++q) {
        size_t o = ((size_t)((b * KYD + ky) * KXD + kx0 + q)) * DVD + dvbase + dv0;
        float2 vr; vr.x = ar[q][0]; vr.y = ar[q][1];
        float2 vi; vi.x = ai[q][0]; vi.y = ai[q][1];
        *(float2*)(Fr + o) = vr;
        *(float2*)(Fi + o) = vi;
    }
}

// K3: channel mix per (kx, i-quad, e-half).  grid = 64*8*2.
__global__ __launch_bounds__(256) void k_mix(const float* __restrict__ Rr,
                                             const float* __restrict__ Ri,
                                             const float* __restrict__ Fr,
                                             const float* __restrict__ Fi,
                                             float* __restrict__ Yr,
                                             float* __restrict__ Yi) {
    __shared__ float fl[2 * 32 * 64 * 2];   // 32 KB, [e2][j][swz(ky)]{fr,fi}
    int kx = blockIdx.x & 63;
    int ig = (blockIdx.x >> 6) & 7;   // 0..7
    int eh = blockIdx.x >> 9;         // 0..1
    int t = threadIdx.x;
    int j = t & 31, kyb = t >> 5;     // kyb 0..7
#pragma unroll
    for (int e2 = 0; e2 < 2; ++e2) {
        int e = eh * 2 + e2;
#pragma unroll
        for (int p = 0; p < 8; ++p) {
            int ky = p * 8 + kyb;
            size_t go = ((size_t)((e * KYD + ky) * KXD + kx)) * DVD + j;
            int lo = ((e2 * 32 + j) * 64 + ((ky + j) & 63)) * 2;
            fl[lo] = Fr[go];
            fl[lo + 1] = Fi[go];
        }
    }
    __syncthreads();
    int lane = t & 63, w = t >> 6;
    int i = ig * 4 + w;
    size_t rb = (size_t)(i * 32) * 4096 + kx * 64 + lane;
    float yr[2] = {}, yi[2] = {};
#pragma unroll 8
    for (int jj = 0; jj < 32; ++jj) {
        float rr = Rr[rb + (size_t)jj * 4096];
        float ri = Ri[rb + (size_t)jj * 4096];
#pragma unroll
        for (int e2 = 0; e2 < 2; ++e2) {
            float2 f = *(const float2*)(fl + ((e2 * 32 + jj) * 64 + ((lane + jj) & 63)) * 2);
            yr[e2] += rr * f.x - ri * f.y;
            yi[e2] += rr * f.y + ri * f.x;
        }
    }
#pragma unroll
    for (int e2 = 0; e2 < 2; ++e2) {
        int e = eh * 2 + e2;
        size_t o = ((size_t)((e * DVD + i) * KXD + kx)) * KYD + lane;
        Yr[o] = yr[e2];
        Yi[o] = yi[e2];
    }
}

// K4: truncated irFFT along NX.  block = (b, i, nx-octant); grid 1024.
__global__ __launch_bounds__(256) void k_irfft(const float* __restrict__ Yr,
                                               const float* __restrict__ Yi,
                                               const float* __restrict__ ws,
                                               float* __restrict__ G) {
    __shared__ __align__(16) float ylr[64 * 64];   // 16 KB [kx][ky], pre-weighted
    __shared__ __align__(16) float yli[64 * 64];
    int blk = blockIdx.x;
    int oct = blk & 7;
    int i = (blk >> 3) & 31;
    int b = blk >> 8;
    int t = threadIdx.x;
    size_t ybase = ((size_t)(b * DVD + i)) * KXD * KYD;
#pragma unroll
    for (int p = 0; p < 4; ++p) {
        int f = p * 256 + t;            // float4 index over 1024; f<16 <=> kx==0
        float wk = (f < 16) ? 1.0f : 2.0f;
        float4 vr = *(const float4*)(Yr + ybase + (size_t)f * 4);
        float4 vi = *(const float4*)(Yi + ybase + (size_t)f * 4);
        vr.x *= wk; vr.y *= wk; vr.z *= wk; vr.w *= wk;
        vi.x *= wk; vi.y *= wk; vi.z *= wk; vi.w *= wk;
        *(float4*)(ylr + f * 4) = vr;
        *(float4*)(yli + f * 4) = vi;
    }
    __syncthreads();
    int kyg = t & 15, nxg = t >> 4;
    int ky0 = kyg * 4;
    int gnx0 = oct * 64 + nxg * 4;
    const float* Tc = ws + OFF_FCN;   // [kx][nx]
    const float* Ts = ws + OFF_FSN;
    float acc[4][4] = {};
    for (int kx = 0; kx < 64; ++kx) {
        float4 cv = *(const float4*)(Tc + kx * 512 + gnx0);
        float4 sv = *(const float4*)(Ts + kx * 512 + gnx0);
        float4 vr = *(const float4*)(ylr + kx * 64 + ky0);
        float4 vi = *(const float4*)(yli + kx * 64 + ky0);
        float ca[4] = {cv.x, cv.y, cv.z, cv.w};
        float sa[4] = {sv.x, sv.y, sv.z, sv.w};
        float ra[4] = {vr.x, vr.y, vr.z, vr.w};
        float ia[4] = {vi.x, vi.y, vi.z, vi.w};
#pragma unroll
        for (int q = 0; q < 4; ++q)
#pragma unroll
            for (int kk = 0; kk < 4; ++kk)
                acc[q][kk] += ca[q] * ra[kk] - sa[q] * ia[kk];
    }
#pragma unroll
    for (int q = 0; q < 4; ++q) {
        float4 v; v.x = acc[q][0]; v.y = acc[q][1]; v.z = acc[q][2]; v.w = acc[q][3];
        *(float4*)(G + (((size_t)(b * NXD + gnx0 + q)) * DVD + i) * KYD + ky0) = v;
    }
}

// K5: iDCT along NY.  block = (b, nx-pair), 256 threads.  Per-thread tile
// 2nx x 4ny x 4i = 32 acc: 12 b128 : 128 FMA per kyc.  gs XOR-swizzled
// (col4 ^= i>>2) -> read starts ((kyc^ig)%8)*4: conflict-free (was 4-way at
// GST=68 = 8.4M conflict cycles at R2).  dn [64ky][128ny] 32 KB single-buffered
// via gload_lds; 48 KB LDS -> 3 blocks/CU.
__global__ __launch_bounds__(256) void k_idct(const float* __restrict__ G,
                                              const float* __restrict__ ws,
                                              float* __restrict__ out) {
    __shared__ __align__(16) float gs[2][2048];   // [n][32i][16col4][4] swizzled, 16 KB
    __shared__ __align__(16) float dn[8192];      // [64ky][128ny] 32 KB
    int b = blockIdx.x >> 8;
    int nx = (blockIdx.x & 255) * 2;
    int t = threadIdx.x;
    int wv = t >> 6;
    int ig = t & 7;          // i0 = ig*4
    int nyg = t >> 3;        // 0..31, ny within chunk = nyg*4..+3
    int i0 = ig * 4;
    const float* Dn = ws + OFF_DN;   // [64ky][512ny]

    auto stage_dn = [&](int c) {
#pragma unroll
        for (int p = 0; p < 8; ++p) {
            int f = p * 256 + t;           // f4 index 0..2047
            int ky = f >> 5, ny4 = (f & 31) * 4;
            gload_lds16(Dn + ky * 512 + c * 128 + ny4, dn + (p * 256 + wv * 64) * 4);
        }
    };

    // stage gs swizzled (regular loads; done before first barrier)
#pragma unroll
    for (int n = 0; n < 2; ++n) {
        const float4* src = (const float4*)(G + (size_t)(b * NXD + nx + n) * DVD * KYD);
#pragma unroll
        for (int p = 0; p < 2; ++p) {
            int f = p * 256 + t;            // 512 f4 = [32i][16col4]
            int i = f >> 4, c4 = f & 15;
            int c4s = (c4 ^ (i >> 2)) & 15;
            *(float4*)(gs[n] + i * 64 + c4s * 4) = src[f];
        }
    }
    stage_dn(0);
    __syncthreads();
    float* outb = out + ((size_t)(b * NXD + nx)) * NYD * DVD;
    for (int c = 0; c < 4; ++c) {
        float acc[2][4][4] = {};   // [n][q=ny][di=i]
#pragma unroll 2
        for (int kyc = 0; kyc < 16; ++kyc) {
            int ky0 = kyc * 4;
            float ga[2][4][4];     // [n][di][kk]
#pragma unroll
            for (int n = 0; n < 2; ++n)
#pragma unroll
                for (int di = 0; di < 4; ++di) {
                    float4 g = *(const float4*)(gs[n] + (i0 + di) * 64 + ((kyc ^ ig) & 15) * 4);
                    ga[n][di][0] = g.x; ga[n][di][1] = g.y;
                    ga[n][di][2] = g.z; ga[n][di][3] = g.w;
                }
#pragma unroll
            for (int kk = 0; kk < 4; ++kk) {
                float4 dv4 = *(const float4*)(dn + (ky0 + kk) * 128 + nyg * 4);
                float dq[4] = {dv4.x, dv4.y, dv4.z, dv4.w};
#pragma unroll
                for (int q = 0; q < 4; ++q)
#pragma unroll
                    for (int n = 0; n < 2; ++n)
#pragma unroll
                        for (int di = 0; di < 4; ++di)
                            acc[n][q][di] += dq[q] * ga[n][di][kk];
            }
        }
#pragma unroll
        for (int n = 0; n < 2; ++n)
#pragma unroll
            for (int q = 0; q < 4; ++q) {
                float4 v; v.x = acc[n][q][0]; v.y = acc[n][q][1];
                v.z = acc[n][q][2]; v.w = acc[n][q][3];
                *(float4*)(outb + ((size_t)(n * NYD + c * 128 + nyg * 4 + q)) * DVD + i0) = v;
            }
        if (c < 3) {
            __syncthreads();       // all reads of dn chunk c done
            stage_dn(c + 1);
            __syncthreads();       // drains staging vmcnt
        }
    }
}

extern "C" void kernel_launch(void* const* d_in, const int* in_sizes, int n_in,
                              void* d_out, int out_size, void* d_ws, size_t ws_size,
                              hipStream_t stream) {
    const float* x  = (const float*)d_in[0];
    const float* Rr = (const float*)d_in[1];
    const float* Ri = (const float*)d_in[2];
    float* out = (float*)d_out;
    float* ws  = (float*)d_ws;
    float* C   = ws + OFF_C;
    float* Fr  = ws + OFF_FR;
    float* Fi  = ws + OFF_FI;
    float* Yr  = ws + OFF_YR;
    float* Yi  = ws + OFF_YI;
    float* G   = ws + OFF_G;

    k_tables<<<128, 256, 0, stream>>>(ws);
    k_dct<<<BB * (NXD / 2), 128, 0, stream>>>(x, ws, C);
    k_rfft<<<BB * KYD * 2, 256, 0, stream>>>(C, ws, Fr, Fi);
    k_mix<<<KXD * 8 * 2, 256, 0, stream>>>(Rr, Ri, Fr, Fi, Yr, Yi);
    k_irfft<<<BB * DVD * 8, 256, 0, stream>>>(Yr, Yi, ws, G);
    k_idct<<<BB * NXD / 2, 256, 0, stream>>>(G, ws, out);
}